// Round 6
// baseline (43.189 us; speedup 1.0000x reference)
//
#include <hip/hip_runtime.h>

// SKA: out[n, g*CW+cw, h, w] = sum_{a,b in 0..2} x[n, g*CW+cw, h+a-1, w+b-1] * w[n, cw, a*3+b, h, w]
// x: (8, 256, 96, 96) f32 ; w: (8, 32, 9, 96, 96) f32 ; out: (8, 256, 96, 96) f32
// Round 5: same no-LDS/shfl-halo design, but x loads batched into an explicit
// xm[8] array per window-row so 8 global_load_dwordx4 stay in flight per wave
// (R4's VGPR=60 showed the compiler serialized load->use chains; force MLP).

#define N_  8
#define C_  256
#define H_  96
#define W_  96
#define CW_ 32
#define G_  8

typedef float f32x4 __attribute__((ext_vector_type(4)));

__global__ __launch_bounds__(256, 4) void SKA_kernel(const float* __restrict__ x,
                                                     const float* __restrict__ wgt,
                                                     float* __restrict__ out) {
    constexpr size_t PLANE = (size_t)H_ * W_;  // 9216

    const int tid   = threadIdx.x;
    const int widx  = tid & 31;   // 0..31, 24 active (w0 = 4*widx < 96)
    const int rowid = tid >> 5;   // 0..7
    const int lane  = tid & 63;   // lane within wave

    const int blk = blockIdx.x;
    const int ht  = blk % (H_ / 8);
    const int t1  = blk / (H_ / 8);
    const int cw  = t1 % CW_;
    const int n   = t1 / CW_;
    const int h   = ht * 8 + rowid;
    const int w0  = widx * 4;

    if (widx >= 24) return;  // padded lanes (96 = 24 float4s per row)

    // ---- 9 per-pixel kernel taps, reused across all 8 groups ----
    const float* wb = wgt + (((size_t)(n * CW_ + cw) * 9) * H_ + (size_t)h) * W_ + w0;
    f32x4 wv[9];
#pragma unroll
    for (int k = 0; k < 9; ++k)
        wv[k] = *reinterpret_cast<const f32x4*>(wb + (size_t)k * PLANE);

    f32x4 acc[G_];
#pragma unroll
    for (int g = 0; g < G_; ++g) acc[g] = (f32x4)(0.f);

    const float* xb = x + ((size_t)n * C_ + cw) * PLANE + w0;

#pragma unroll
    for (int a = 0; a < 3; ++a) {
        const int hh = h + a - 1;
        if (hh < 0 || hh >= H_) continue;  // zero padding rows
        const f32x4 w0v = wv[a * 3 + 0];
        const f32x4 w1v = wv[a * 3 + 1];
        const f32x4 w2v = wv[a * 3 + 2];

        // batch all 8 group loads -> 8 independent dwordx4 in flight
        f32x4 xm[G_];
#pragma unroll
        for (int g = 0; g < G_; ++g)
            xm[g] = *reinterpret_cast<const f32x4*>(
                xb + (size_t)(g * CW_) * PLANE + (size_t)hh * W_);

#pragma unroll
        for (int g = 0; g < G_; ++g) {
            // halo via cross-lane exchange (lane stride 1 == 4 floats in w)
            float xl = __shfl(xm[g].w, lane - 1);
            float xr = __shfl(xm[g].x, lane + 1);
            xl = (widx == 0) ? 0.f : xl;   // x[-1] pad
            xr = (widx == 23) ? 0.f : xr;  // x[96] pad
            acc[g].x = fmaf(xl,      w0v.x, acc[g].x);
            acc[g].x = fmaf(xm[g].x, w1v.x, acc[g].x);
            acc[g].x = fmaf(xm[g].y, w2v.x, acc[g].x);
            acc[g].y = fmaf(xm[g].x, w0v.y, acc[g].y);
            acc[g].y = fmaf(xm[g].y, w1v.y, acc[g].y);
            acc[g].y = fmaf(xm[g].z, w2v.y, acc[g].y);
            acc[g].z = fmaf(xm[g].y, w0v.z, acc[g].z);
            acc[g].z = fmaf(xm[g].z, w1v.z, acc[g].z);
            acc[g].z = fmaf(xm[g].w, w2v.z, acc[g].z);
            acc[g].w = fmaf(xm[g].z, w0v.w, acc[g].w);
            acc[g].w = fmaf(xm[g].w, w1v.w, acc[g].w);
            acc[g].w = fmaf(xr,      w2v.w, acc[g].w);
        }
    }

    float* ob = out + ((size_t)n * C_ + cw) * PLANE + (size_t)h * W_ + w0;
#pragma unroll
    for (int g = 0; g < G_; ++g) {
        __builtin_nontemporal_store(
            acc[g], reinterpret_cast<f32x4*>(ob + (size_t)(g * CW_) * PLANE));
    }
}

extern "C" void kernel_launch(void* const* d_in, const int* in_sizes, int n_in,
                              void* d_out, int out_size, void* d_ws, size_t ws_size,
                              hipStream_t stream) {
    const float* x   = (const float*)d_in[0];
    const float* wgt = (const float*)d_in[1];
    float* out = (float*)d_out;

    constexpr int grid = N_ * CW_ * (H_ / 8);  // 3072 blocks x 256 threads
    SKA_kernel<<<grid, 256, 0, stream>>>(x, wgt, out);
}